// Round 1
// baseline (184.867 us; speedup 1.0000x reference)
//
#include <hip/hip_runtime.h>

// VectorQuantizer: z_e [16,1024,256] f32, codebook [1024,256] f32
// out = concat( z_q [16,1024,256] f32 , indices [16,1024] as f32 )
//
// M = 16384 rows, D = 256, NC = 1024 codes.
// score(r,c) = ||c||^2 - 2 * dot(z_r, c); argmin over c; z_q = codebook[argmin].

#define M_ROWS 16384
#define DDIM   256
#define NCODES 1024

// ---------------- c_sq: one wave per code ----------------
__global__ __launch_bounds__(256) void vq_csq_kernel(const float* __restrict__ cb,
                                                     float* __restrict__ csq) {
    const int code = blockIdx.x * 4 + (threadIdx.x >> 6);
    const int lane = threadIdx.x & 63;
    const float4 v = *reinterpret_cast<const float4*>(cb + code * DDIM + lane * 4);
    float s = v.x * v.x + v.y * v.y + v.z * v.z + v.w * v.w;
#pragma unroll
    for (int off = 32; off > 0; off >>= 1) s += __shfl_down(s, off, 64);
    if (lane == 0) csq[code] = s;
}

// ---------------- main score + argmin ----------------
// Block: 256 threads, 64 rows. Loops over 16 code-tiles of 64 codes,
// K staged in chunks of 32. 4x4 register micro-tile per thread.
__global__ __launch_bounds__(256) void vq_score_kernel(const float* __restrict__ z,
                                                       const float* __restrict__ cb,
                                                       const float* __restrict__ csq,
                                                       float* __restrict__ outIdx) {
    __shared__ __align__(16) float As[32][68];   // [k][row], pad 68 -> 2-way max
    __shared__ __align__(16) float Bs[32][68];   // [k][code]
    __shared__ float redv[64][17];
    __shared__ int   redi[64][17];

    const int tid  = threadIdx.x;
    const int rowL = tid >> 2;      // 0..63  (staging row / code)
    const int qq   = tid & 3;       // 0..3   (staging k-quad)
    const int tx   = tid & 15;      // compute: code group
    const int ty   = tid >> 4;      // compute: row group
    const int rowBase = blockIdx.x * 64;

    float minv[4];
    int   mini[4];
#pragma unroll
    for (int i = 0; i < 4; ++i) { minv[i] = 3.4e38f; mini[i] = 0; }

    const float* zrow = z  + (rowBase + rowL) * DDIM;

    for (int nt = 0; nt < 16; ++nt) {
        float acc[4][4];
#pragma unroll
        for (int i = 0; i < 4; ++i)
#pragma unroll
            for (int j = 0; j < 4; ++j) acc[i][j] = 0.0f;

        const float* crow = cb + (nt * 64 + rowL) * DDIM;

        for (int kc = 0; kc < 8; ++kc) {
            const int k0 = kc * 32;
            __syncthreads();
            // stage A (64 rows x 32 k) and B (64 codes x 32 k), transposed to [k][*]
            const float4 a0 = *reinterpret_cast<const float4*>(zrow + k0 + qq * 4);
            const float4 a1 = *reinterpret_cast<const float4*>(zrow + k0 + 16 + qq * 4);
            const float4 b0 = *reinterpret_cast<const float4*>(crow + k0 + qq * 4);
            const float4 b1 = *reinterpret_cast<const float4*>(crow + k0 + 16 + qq * 4);
            As[qq * 4 + 0][rowL] = a0.x;  As[qq * 4 + 1][rowL] = a0.y;
            As[qq * 4 + 2][rowL] = a0.z;  As[qq * 4 + 3][rowL] = a0.w;
            As[16 + qq * 4 + 0][rowL] = a1.x;  As[16 + qq * 4 + 1][rowL] = a1.y;
            As[16 + qq * 4 + 2][rowL] = a1.z;  As[16 + qq * 4 + 3][rowL] = a1.w;
            Bs[qq * 4 + 0][rowL] = b0.x;  Bs[qq * 4 + 1][rowL] = b0.y;
            Bs[qq * 4 + 2][rowL] = b0.z;  Bs[qq * 4 + 3][rowL] = b0.w;
            Bs[16 + qq * 4 + 0][rowL] = b1.x;  Bs[16 + qq * 4 + 1][rowL] = b1.y;
            Bs[16 + qq * 4 + 2][rowL] = b1.z;  Bs[16 + qq * 4 + 3][rowL] = b1.w;
            __syncthreads();

#pragma unroll
            for (int k = 0; k < 32; ++k) {
                const float4 av = *reinterpret_cast<const float4*>(&As[k][ty * 4]);
                const float4 bv = *reinterpret_cast<const float4*>(&Bs[k][tx * 4]);
                acc[0][0] += av.x * bv.x; acc[0][1] += av.x * bv.y;
                acc[0][2] += av.x * bv.z; acc[0][3] += av.x * bv.w;
                acc[1][0] += av.y * bv.x; acc[1][1] += av.y * bv.y;
                acc[1][2] += av.y * bv.z; acc[1][3] += av.y * bv.w;
                acc[2][0] += av.z * bv.x; acc[2][1] += av.z * bv.y;
                acc[2][2] += av.z * bv.z; acc[2][3] += av.z * bv.w;
                acc[3][0] += av.w * bv.x; acc[3][1] += av.w * bv.y;
                acc[3][2] += av.w * bv.z; acc[3][3] += av.w * bv.w;
            }
        }

        // fold this code-tile into the running argmin
        const int codeBase = nt * 64 + tx * 4;
        const float4 c4 = *reinterpret_cast<const float4*>(csq + codeBase);
        const float cs[4] = { c4.x, c4.y, c4.z, c4.w };
#pragma unroll
        for (int i = 0; i < 4; ++i) {
#pragma unroll
            for (int j = 0; j < 4; ++j) {
                const float s = cs[j] - 2.0f * acc[i][j];
                if (s < minv[i]) { minv[i] = s; mini[i] = codeBase + j; }
            }
        }
    }

    // block-level reduce across the 16 tx groups
    __syncthreads();
#pragma unroll
    for (int i = 0; i < 4; ++i) {
        redv[ty * 4 + i][tx] = minv[i];
        redi[ty * 4 + i][tx] = mini[i];
    }
    __syncthreads();
    if (tid < 64) {
        float bv = redv[tid][0];
        int   bi = redi[tid][0];
#pragma unroll
        for (int t = 1; t < 16; ++t) {
            const float v = redv[tid][t];
            const int   ii = redi[tid][t];
            if (v < bv || (v == bv && ii < bi)) { bv = v; bi = ii; }
        }
        outIdx[rowBase + tid] = (float)bi;
    }
}

// ---------------- gather z_q = codebook[idx] ----------------
__global__ __launch_bounds__(256) void vq_gather_kernel(const float* __restrict__ cb,
                                                        const float* __restrict__ idxF,
                                                        float* __restrict__ zq) {
    const int row  = blockIdx.x * 4 + (threadIdx.x >> 6);
    const int lane = threadIdx.x & 63;
    const int idx  = (int)idxF[row];
    const float4 v = *reinterpret_cast<const float4*>(cb + idx * DDIM + lane * 4);
    *reinterpret_cast<float4*>(zq + row * DDIM + lane * 4) = v;
}

extern "C" void kernel_launch(void* const* d_in, const int* in_sizes, int n_in,
                              void* d_out, int out_size, void* d_ws, size_t ws_size,
                              hipStream_t stream) {
    const float* z  = (const float*)d_in[0];   // [16,1024,256]
    const float* cb = (const float*)d_in[1];   // [1024,256]
    float* out    = (float*)d_out;
    float* zq     = out;                       // 16*1024*256 floats
    float* outIdx = out + (size_t)M_ROWS * DDIM; // 16384 floats
    float* csq    = (float*)d_ws;              // 1024 floats scratch

    vq_csq_kernel<<<NCODES / 4, 256, 0, stream>>>(cb, csq);
    vq_score_kernel<<<M_ROWS / 64, 256, 0, stream>>>(z, cb, csq, outIdx);
    vq_gather_kernel<<<M_ROWS / 4, 256, 0, stream>>>(cb, outIdx, zq);
}

// Round 2
// 117.608 us; speedup vs baseline: 1.5719x; 1.5719x over previous
//
#include <hip/hip_runtime.h>

// VectorQuantizer: z_e [16,1024,256] f32, codebook [1024,256] f32
// out = concat( z_q [16,1024,256] f32 , indices [16,1024] as f32 )
// score(r,c) = ||c||^2 - 2*dot(z_r,c); argmin over c; z_q = codebook[argmin].

#define M_ROWS 16384
#define DDIM   256
#define NCODES 1024
#define PADW   132   // 128 + 4 pad (stride mod 32 = 4)

// sortable encoding: order-preserving f32 -> u32 (no NaNs in scores)
__device__ __forceinline__ unsigned int f2ord(float f) {
    unsigned int u = __float_as_uint(f);
    return (u & 0x80000000u) ? ~u : (u | 0x80000000u);
}

// ---------------- init row minima ----------------
__global__ __launch_bounds__(256) void vq_init_kernel(unsigned long long* __restrict__ rowmin) {
    const int i = blockIdx.x * 256 + threadIdx.x;
    rowmin[i] = ~0ULL;
}

// ---------------- c_sq: one wave per code ----------------
__global__ __launch_bounds__(256) void vq_csq_kernel(const float* __restrict__ cb,
                                                     float* __restrict__ csq) {
    const int code = blockIdx.x * 4 + (threadIdx.x >> 6);
    const int lane = threadIdx.x & 63;
    const float4 v = *reinterpret_cast<const float4*>(cb + code * DDIM + lane * 4);
    float s = v.x * v.x + v.y * v.y + v.z * v.z + v.w * v.w;
#pragma unroll
    for (int off = 32; off > 0; off >>= 1) s += __shfl_down(s, off, 64);
    if (lane == 0) csq[code] = s;
}

// ---------------- main score + fused per-tile argmin ----------------
// grid (128 row-tiles, 8 code-chunks), 256 threads. Tile 128 rows x 128 codes,
// 8x8 register micro-tile per thread, K staged in chunks of 16.
__global__ __launch_bounds__(256, 4) void vq_score_kernel(const float* __restrict__ z,
                                                          const float* __restrict__ cb,
                                                          const float* __restrict__ csq,
                                                          unsigned long long* __restrict__ rowmin) {
    __shared__ __align__(16) float As[16][PADW];   // [k][row]
    __shared__ __align__(16) float Bs[16][PADW];   // [k][code]
    __shared__ unsigned long long red[128][17];

    const int tid = threadIdx.x;
    const int tx  = tid & 15;       // code group
    const int ty  = tid >> 4;       // row group
    const int rowBase  = blockIdx.x * 128;
    const int codeBase = blockIdx.y * 128;

    // staging ids: 64 base-rows x 4 k-quads
    const int srow = tid >> 2;      // 0..63
    const int sq   = tid & 3;       // 0..3
    const float* zr0 = z  + (size_t)(rowBase  + srow)      * DDIM;
    const float* zr1 = z  + (size_t)(rowBase  + srow + 64) * DDIM;
    const float* cr0 = cb + (size_t)(codeBase + srow)      * DDIM;
    const float* cr1 = cb + (size_t)(codeBase + srow + 64) * DDIM;

    float acc[8][8];
#pragma unroll
    for (int i = 0; i < 8; ++i)
#pragma unroll
        for (int j = 0; j < 8; ++j) acc[i][j] = 0.0f;

    for (int kc = 0; kc < 16; ++kc) {
        const int k0 = kc * 16;
        __syncthreads();
        const float4 a0 = *reinterpret_cast<const float4*>(zr0 + k0 + sq * 4);
        const float4 a1 = *reinterpret_cast<const float4*>(zr1 + k0 + sq * 4);
        const float4 b0 = *reinterpret_cast<const float4*>(cr0 + k0 + sq * 4);
        const float4 b1 = *reinterpret_cast<const float4*>(cr1 + k0 + sq * 4);
        As[sq * 4 + 0][srow] = a0.x;  As[sq * 4 + 1][srow] = a0.y;
        As[sq * 4 + 2][srow] = a0.z;  As[sq * 4 + 3][srow] = a0.w;
        As[sq * 4 + 0][srow + 64] = a1.x;  As[sq * 4 + 1][srow + 64] = a1.y;
        As[sq * 4 + 2][srow + 64] = a1.z;  As[sq * 4 + 3][srow + 64] = a1.w;
        Bs[sq * 4 + 0][srow] = b0.x;  Bs[sq * 4 + 1][srow] = b0.y;
        Bs[sq * 4 + 2][srow] = b0.z;  Bs[sq * 4 + 3][srow] = b0.w;
        Bs[sq * 4 + 0][srow + 64] = b1.x;  Bs[sq * 4 + 1][srow + 64] = b1.y;
        Bs[sq * 4 + 2][srow + 64] = b1.z;  Bs[sq * 4 + 3][srow + 64] = b1.w;
        __syncthreads();

#pragma unroll
        for (int k = 0; k < 16; ++k) {
            const float4 av0 = *reinterpret_cast<const float4*>(&As[k][ty * 4]);
            const float4 av1 = *reinterpret_cast<const float4*>(&As[k][64 + ty * 4]);
            const float4 bv0 = *reinterpret_cast<const float4*>(&Bs[k][tx * 4]);
            const float4 bv1 = *reinterpret_cast<const float4*>(&Bs[k][64 + tx * 4]);
            const float a[8] = { av0.x, av0.y, av0.z, av0.w, av1.x, av1.y, av1.z, av1.w };
            const float b[8] = { bv0.x, bv0.y, bv0.z, bv0.w, bv1.x, bv1.y, bv1.z, bv1.w };
#pragma unroll
            for (int i = 0; i < 8; ++i)
#pragma unroll
                for (int j = 0; j < 8; ++j) acc[i][j] += a[i] * b[j];
        }
    }

    // epilogue: per-thread argmin over its 8 codes, per row
    int codeId[8];
    float cs[8];
#pragma unroll
    for (int j = 0; j < 8; ++j) {
        codeId[j] = codeBase + ((j < 4) ? (tx * 4 + j) : (64 + tx * 4 + (j - 4)));
        cs[j] = csq[codeId[j]];
    }
    unsigned long long bestKey[8];
#pragma unroll
    for (int i = 0; i < 8; ++i) {
        unsigned long long bk = ~0ULL;
#pragma unroll
        for (int j = 0; j < 8; ++j) {
            const float s = cs[j] - 2.0f * acc[i][j];
            const unsigned long long key =
                ((unsigned long long)f2ord(s) << 32) | (unsigned int)codeId[j];
            bk = (key < bk) ? key : bk;
        }
        bestKey[i] = bk;
    }

    // cross-tx reduce in LDS, then one atomicMin per row
    __syncthreads();
#pragma unroll
    for (int i = 0; i < 8; ++i) {
        const int rloc = (i < 4) ? (ty * 4 + i) : (64 + ty * 4 + (i - 4));
        red[rloc][tx] = bestKey[i];
    }
    __syncthreads();
    if (tid < 128) {
        unsigned long long bk = red[tid][0];
#pragma unroll
        for (int t = 1; t < 16; ++t) {
            const unsigned long long v = red[tid][t];
            bk = (v < bk) ? v : bk;
        }
        atomicMin(&rowmin[rowBase + tid], bk);
    }
}

// ---------------- gather z_q = codebook[idx], emit indices ----------------
__global__ __launch_bounds__(256) void vq_gather_kernel(const float* __restrict__ cb,
                                                        const unsigned long long* __restrict__ rowmin,
                                                        float* __restrict__ zq,
                                                        float* __restrict__ outIdx) {
    const int row  = blockIdx.x * 4 + (threadIdx.x >> 6);
    const int lane = threadIdx.x & 63;
    const int idx  = (int)(unsigned int)(rowmin[row] & 0xFFFFFFFFULL);
    if (lane == 0) outIdx[row] = (float)idx;
    const float4 v = *reinterpret_cast<const float4*>(cb + (size_t)idx * DDIM + lane * 4);
    *reinterpret_cast<float4*>(zq + (size_t)row * DDIM + lane * 4) = v;
}

extern "C" void kernel_launch(void* const* d_in, const int* in_sizes, int n_in,
                              void* d_out, int out_size, void* d_ws, size_t ws_size,
                              hipStream_t stream) {
    const float* z  = (const float*)d_in[0];   // [16,1024,256]
    const float* cb = (const float*)d_in[1];   // [1024,256]
    float* out    = (float*)d_out;
    float* zq     = out;                           // 16*1024*256 floats
    float* outIdx = out + (size_t)M_ROWS * DDIM;   // 16384 floats

    unsigned long long* rowmin = (unsigned long long*)d_ws;            // 16384 u64
    float* csq = (float*)((char*)d_ws + (size_t)M_ROWS * 8);           // 1024 f32

    vq_init_kernel<<<M_ROWS / 256, 256, 0, stream>>>(rowmin);
    vq_csq_kernel<<<NCODES / 4, 256, 0, stream>>>(cb, csq);
    dim3 grid(M_ROWS / 128, NCODES / 128);
    vq_score_kernel<<<grid, 256, 0, stream>>>(z, cb, csq, rowmin);
    vq_gather_kernel<<<M_ROWS / 4, 256, 0, stream>>>(cb, rowmin, zq, outIdx);
}